// Round 5
// baseline (200.840 us; speedup 1.0000x reference)
//
#include <hip/hip_runtime.h>

// DenseLayerWithComplexNeurons: out = per-cell-type-MLP( x @ W^T + b )
// M = B*S = 8192, K = DIN = 1024, N = A*DOUT = 4096, DOUT = 1024
// T = 4 cell types, G = 256 neurons/type, A = 4, H = 8.
//
// Round 1: bf16 MFMA GEMM 128x128/BK64, fused LDS epilogue. 154.5 us.
// Round 2: XOR-swizzled staging -> 0 conflicts, 118.9 us.
// Round 3: 256x128 block, 128x64 wave tiles, 32x32x16 MFMA. 101.6 us.
// Rounds 4-7: 256x256 8-wave 4-phase pipelines (counted vmcnt, setprio,
//   balanced reads): 134.4 / 118.4 / FAIL / 112.8 us -- ALL worse than R3.
//   Lesson: at 128 KiB LDS the kernel is 1 block/CU; the all-wave barrier
//   lockstep exposes every residual stall. R3's 2 blocks/CU hide them via
//   TLP (m114 implicit overlap). Also: the 6.29M SQ_LDS_BANK_CONFLICT is
//   exactly 4 cyc per ds_read_b128 (m134's 12-vs-8 cyc overhead), NOT a
//   layout conflict -- epilogue layout is already conflict-free.
// Round 8: R3 kernel verbatim, __launch_bounds__(256,3): 3 blocks/CU
//   (LDS 3x48K=144K <= 160K; VGPR 104 -> 4 waves/SIMD OK). Third block
//   fills the staging-drain bubble.

typedef __bf16 bf16x8 __attribute__((ext_vector_type(8)));
typedef float f32x4 __attribute__((ext_vector_type(4)));
typedef float f32x16 __attribute__((ext_vector_type(16)));

#define BM 256
#define BN 128
#define BK 64
#define KDIM 1024
#define A_ELEMS (BM * BK)            // 16384 bf16 = 32 KB
#define ZSTRIDE 132                  // floats; 132%32=4 keeps b32 write halves conflict-free
#define XN8 (8192 * 1024 / 8)
#define WN8 (4096 * 1024 / 8)

__global__ __launch_bounds__(256) void cvt_bf16_kernel(
    const float* __restrict__ x, const float* __restrict__ w,
    __bf16* __restrict__ xb, __bf16* __restrict__ wb) {
    int i = blockIdx.x * 256 + threadIdx.x;
    const float* src;
    __bf16* dst;
    int j;
    if (i < XN8) { src = x; dst = xb; j = i; }
    else         { src = w; dst = wb; j = i - XN8; }
    const f32x4* p = (const f32x4*)src + 2 * (size_t)j;
    f32x4 a = p[0], b = p[1];
    bf16x8 o;
    o[0] = (__bf16)a[0]; o[1] = (__bf16)a[1]; o[2] = (__bf16)a[2]; o[3] = (__bf16)a[3];
    o[4] = (__bf16)b[0]; o[5] = (__bf16)b[1]; o[6] = (__bf16)b[2]; o[7] = (__bf16)b[3];
    ((bf16x8*)dst)[j] = o;
}

union __align__(16) SmemU {
    __bf16 stg[A_ELEMS + BN * BK];   // A tile (256x64) then B tile (128x64); 16B chunk c stored at c^(row&7)
    float  z[64 * ZSTRIDE];          // one 64-row slab of the z tile, [m][n] padded
};

__global__ __launch_bounds__(256, 3) void fused_gemm_mlp_kernel(
    const __bf16* __restrict__ Ag,   // [8192][1024] bf16 (x)
    const __bf16* __restrict__ Bg,   // [4096][1024] bf16 (weight, already B^T layout)
    const float* __restrict__ bias,  // [4096]
    const float* __restrict__ cw1,   // [4][4][8]
    const float* __restrict__ cb1,   // [4][8]
    const float* __restrict__ cw2,   // [4][8]
    const float* __restrict__ cb2,   // [4]
    float* __restrict__ out)         // [8192][1024]
{
    __shared__ SmemU u;

    const int tid  = threadIdx.x;
    const int wave = tid >> 6;
    const int lane = tid & 63;
    const int wm = wave >> 1;        // row half (0..1): 128 rows each
    const int wn = wave & 1;         // col half (0..1): 64 cols each
    const int bn0 = blockIdx.x * BN; // n offset in [0,4096)
    const int bm0 = blockIdx.y * BM; // m offset in [0,8192)

    f32x16 acc[4][2] = {};           // 4 m-tiles x 2 n-tiles of 32x32

    // ---- staging lane mapping (XOR swizzle, per 8-row chunk) ----
    const int srow  = lane >> 3;
    const int scol8 = (((lane & 7) ^ srow) * 8);

    // ---- fragment LDS base addresses per k-step (hoisted) ----
    // A-frag 32x32x16: row = lane&31, k = (lane>>5)*8 + i  (B mirrors with col)
    const int lr5 = lane & 31;
    const int lk2 = lane >> 5;   // 0..1
    const int lx  = lane & 7;
    int a_base[4], b_base[4];
#pragma unroll
    for (int kh = 0; kh < 4; ++kh) {
        const int cx = ((kh * 2 + lk2) ^ lx) * 16;  // swizzled 16B chunk byte offset
        a_base[kh] = (wm * 128 + lr5) * (BK * 2) + cx;
        b_base[kh] = A_ELEMS * 2 + (wn * 64 + lr5) * (BK * 2) + cx;
    }
    const char* sb = (const char*)u.stg;

    for (int k0 = 0; k0 < KDIM; k0 += BK) {
        // ---- stage A (256x64) + B (128x64) via global_load_lds width=16 ----
#pragma unroll
        for (int c = 0; c < 8; ++c) {  // A: 32 chunks of 8 rows, 8 per wave
            const int chunk = wave + c * 4;
            const __bf16* ga = Ag + (size_t)(bm0 + chunk * 8 + srow) * KDIM + k0 + scol8;
            __builtin_amdgcn_global_load_lds(
                (__attribute__((address_space(1))) void*)ga,
                (__attribute__((address_space(3))) void*)&u.stg[chunk * 8 * BK],
                16, 0, 0);
        }
#pragma unroll
        for (int c = 0; c < 4; ++c) {  // B: 16 chunks of 8 rows, 4 per wave
            const int chunk = wave + c * 4;
            const __bf16* gb = Bg + (size_t)(bn0 + chunk * 8 + srow) * KDIM + k0 + scol8;
            __builtin_amdgcn_global_load_lds(
                (__attribute__((address_space(1))) void*)gb,
                (__attribute__((address_space(3))) void*)&u.stg[A_ELEMS + chunk * 8 * BK],
                16, 0, 0);
        }
        __syncthreads();

        // ---- MFMA: 4 k-steps of 16 ----
#pragma unroll
        for (int kh = 0; kh < 4; ++kh) {
            bf16x8 af[4], bfr[2];
#pragma unroll
            for (int mi = 0; mi < 4; ++mi)
                af[mi] = *(const bf16x8*)(sb + a_base[kh] + mi * 4096);
#pragma unroll
            for (int ni = 0; ni < 2; ++ni)
                bfr[ni] = *(const bf16x8*)(sb + b_base[kh] + ni * 4096);
#pragma unroll
            for (int mi = 0; mi < 4; ++mi)
#pragma unroll
                for (int ni = 0; ni < 2; ++ni)
                    acc[mi][ni] = __builtin_amdgcn_mfma_f32_32x32x16_bf16(
                        af[mi], bfr[ni], acc[mi][ni], 0, 0, 0);
        }
        __syncthreads();
    }

    // ---- epilogue: per-neuron MLP over A=4 adjacent z columns ----
    const int t = bn0 >> 10;  // cell type, block-uniform
    float w1[32], b1[8], w2[8];
#pragma unroll
    for (int i = 0; i < 32; ++i) w1[i] = cw1[t * 32 + i];
#pragma unroll
    for (int i = 0; i < 8; ++i) { b1[i] = cb1[t * 8 + i]; w2[i] = cw2[t * 8 + i]; }
    const float b2 = cb2[t];

    float bcol[2];
#pragma unroll
    for (int ni = 0; ni < 2; ++ni)
        bcol[ni] = bias[bn0 + wn * 64 + ni * 32 + lr5];

    const float L2E2 = 2.885390081777927f;  // 2*log2(e)

#pragma unroll
    for (int h = 0; h < 4; ++h) {  // 64-row slabs
        if (wm == (h >> 1)) {
            const int mi0 = (h & 1) * 2;
#pragma unroll
            for (int dmi = 0; dmi < 2; ++dmi) {
                const int mi = mi0 + dmi;
#pragma unroll
                for (int ni = 0; ni < 2; ++ni) {
                    const int n = wn * 64 + ni * 32 + lr5;
#pragma unroll
                    for (int g = 0; g < 4; ++g) {
                        // C/D 32x32 layout: col=lane&31, row=(reg&3)+8*(reg>>2)+4*(lane>>5)
                        const int rb = dmi * 32 + g * 8 + lk2 * 4;
                        u.z[(rb + 0) * ZSTRIDE + n] = acc[mi][ni][g * 4 + 0] + bcol[ni];
                        u.z[(rb + 1) * ZSTRIDE + n] = acc[mi][ni][g * 4 + 1] + bcol[ni];
                        u.z[(rb + 2) * ZSTRIDE + n] = acc[mi][ni][g * 4 + 2] + bcol[ni];
                        u.z[(rb + 3) * ZSTRIDE + n] = acc[mi][ni][g * 4 + 3] + bcol[ni];
                    }
                }
            }
        }
        __syncthreads();

        // 64 rows x 32 neurons = 2048 outputs; 8 per thread
#pragma unroll
        for (int it = 0; it < 8; ++it) {
            const int i = tid + it * 256;
            const int q = i & 31;       // neuron within block
            const int r = i >> 5;       // row within slab
            f32x4 z = *(const f32x4*)&u.z[r * ZSTRIDE + 4 * q];
            float o = 0.f;
#pragma unroll
            for (int hh = 0; hh < 8; ++hh) {
                float pre = z[0] * w1[0 * 8 + hh] + z[1] * w1[1 * 8 + hh]
                          + z[2] * w1[2 * 8 + hh] + z[3] * w1[3 * 8 + hh] + b1[hh];
                float e = __builtin_amdgcn_exp2f(pre * L2E2);        // e^(2*pre)
                float th = 1.0f - 2.0f * __builtin_amdgcn_rcpf(e + 1.0f);
                o += th * w2[hh];
            }
            o += b2;
            out[(size_t)(bm0 + h * 64 + r) * 1024 + (bn0 >> 2) + q] = o;
        }
        __syncthreads();
    }
}

extern "C" void kernel_launch(void* const* d_in, const int* in_sizes, int n_in,
                              void* d_out, int out_size, void* d_ws, size_t ws_size,
                              hipStream_t stream) {
    const float* x    = (const float*)d_in[0];
    const float* w    = (const float*)d_in[1];
    const float* bias = (const float*)d_in[2];
    const float* cw1  = (const float*)d_in[3];
    const float* cb1  = (const float*)d_in[4];
    const float* cw2  = (const float*)d_in[5];
    const float* cb2  = (const float*)d_in[6];
    float* out = (float*)d_out;

    __bf16* xb = (__bf16*)d_ws;                       // 8192*1024 bf16 = 16 MB
    __bf16* wb = xb + (size_t)8192 * 1024;            // 4096*1024 bf16 = 8 MB

    cvt_bf16_kernel<<<(XN8 + WN8) / 256, 256, 0, stream>>>(x, w, xb, wb);

    dim3 grid(4096 / BN, 8192 / BM);  // (32, 32)
    fused_gemm_mlp_kernel<<<grid, 256, 0, stream>>>(xb, wb, bias, cw1, cb1, cw2, cb2, out);
}

// Round 6
// 192.038 us; speedup vs baseline: 1.0458x; 1.0458x over previous
//
#include <hip/hip_runtime.h>

// DenseLayerWithComplexNeurons: out = per-cell-type-MLP( x @ W^T + b )
// M = B*S = 8192, K = DIN = 1024, N = A*DOUT = 4096, DOUT = 1024
// T = 4 cell types, G = 256 neurons/type, A = 4, H = 8.
//
// Round 3: 256x128 block, BK=64 single-buffer, 2-barrier loop. 101.6 us
//   (MfmaUtil 29%). Stall: stage-issue immediately followed by
//   __syncthreads whose implicit vmcnt(0) exposes full DMA latency 16x.
// Rounds 4-7: 256x256 1-block/CU pipelines: 134/118/FAIL/113 us. Lockstep
//   of all 8 waves behind one barrier chain is worse than 2-block TLP.
// Round 8: launch_bounds(256,3): VGPR 104->84 forced acc spills
//   (WRITE_SIZE +23MB scratch). 113.5 us. 2 blocks/CU is register-structural
//   (128 acc floats/thread); occupancy is NOT a free knob here.
// Round 9: BK=32 double-buffer in the SAME 48K LDS; loop order
//   {stage(t+1)->nbuf; compute(t)<-cbuf; __syncthreads()}. The barrier's
//   implicit vmcnt(0) drain now lands after a full compute phase -> DMA
//   latency hidden; still 2 blocks/CU; one barrier per K-tile (32 total,
//   same count as R3). BK=32 rows stored as row-PAIRS in 128B physical
//   rows, slot = ((r&1)*4+c)^((r>>1)&7): 2 lanes/slot per 16-lane group
//   on ds_read_b128 (2-way = free, m136).

typedef __bf16 bf16x8 __attribute__((ext_vector_type(8)));
typedef float f32x4 __attribute__((ext_vector_type(4)));
typedef float f32x16 __attribute__((ext_vector_type(16)));

#define BM 256
#define BN 128
#define BK 32
#define KDIM 1024
#define NT 32                        // K / BK
#define ABUF 16384                   // A bytes per buffer (256 rows x 32 k x 2B)
#define BUFB 24576                   // per-buffer bytes: A 16K + B 8K
#define ZSTRIDE 132                  // floats; epilogue layout (verified R3)
#define XN8 (8192 * 1024 / 8)
#define WN8 (4096 * 1024 / 8)

__global__ __launch_bounds__(256) void cvt_bf16_kernel(
    const float* __restrict__ x, const float* __restrict__ w,
    __bf16* __restrict__ xb, __bf16* __restrict__ wb) {
    int i = blockIdx.x * 256 + threadIdx.x;
    const float* src;
    __bf16* dst;
    int j;
    if (i < XN8) { src = x; dst = xb; j = i; }
    else         { src = w; dst = wb; j = i - XN8; }
    const f32x4* p = (const f32x4*)src + 2 * (size_t)j;
    f32x4 a = p[0], b = p[1];
    bf16x8 o;
    o[0] = (__bf16)a[0]; o[1] = (__bf16)a[1]; o[2] = (__bf16)a[2]; o[3] = (__bf16)a[3];
    o[4] = (__bf16)b[0]; o[5] = (__bf16)b[1]; o[6] = (__bf16)b[2]; o[7] = (__bf16)b[3];
    ((bf16x8*)dst)[j] = o;
}

union __align__(16) SmemU {
    unsigned char raw[2 * BUFB];     // 49152 B: two {A|B} BK=32 buffers
    float z[64 * ZSTRIDE];           // 33792 B epilogue slab
};

__global__ __launch_bounds__(256, 2) void fused_gemm_mlp_kernel(
    const __bf16* __restrict__ Ag,   // [8192][1024] bf16 (x)
    const __bf16* __restrict__ Bg,   // [4096][1024] bf16 (weight, B^T layout)
    const float* __restrict__ bias,  // [4096]
    const float* __restrict__ cw1,   // [4][4][8]
    const float* __restrict__ cb1,   // [4][8]
    const float* __restrict__ cw2,   // [4][8]
    const float* __restrict__ cb2,   // [4]
    float* __restrict__ out)         // [8192][1024]
{
    __shared__ SmemU u;

    const int tid  = threadIdx.x;
    const int wave = tid >> 6;
    const int lane = tid & 63;
    const int wm = wave >> 1;        // row half (0..1): 128 rows each
    const int wn = wave & 1;         // col half (0..1): 64 cols each
    const int bn0 = blockIdx.x * BN; // n offset in [0,4096)
    const int bm0 = blockIdx.y * BM; // m offset in [0,8192)

    f32x16 acc[4][2] = {};           // 4 m-tiles x 2 n-tiles of 32x32

    // ---- staging lane mapping ----
    // 1KB DMA chunk = 16 rows (8 row-pairs x 128B). Lane i writes byte 16*i:
    // q_loc = i>>3 (row-pair), phys slot = i&7. Inverse (global source):
    // s_log = slot ^ q_loc; row-in-chunk = 2*q_loc + (s_log>>2); col16 = s_log&3.
    // Element check: global (R, c) lands at chunk*1024 + (R>>1 &7)*128 +
    // (((R&1)*4+c)^((R>>1)&7))*16 == fragment-read address below.  [verified]
    const int qloc = lane >> 3;
    const int slog = (lane & 7) ^ qloc;
    const int arow = 2 * qloc + (slog >> 2);   // row within 16-row chunk
    const int acol = (slog & 3) * 8;           // bf16 col offset within BK

    // ---- fragment LDS byte addresses (buffer-relative), hoisted ----
    // MFMA 32x32x16: row = lane&31, k = kh*16 + (lane>>5)*8 + i.
    // phys: q = row>>1 (128B rows), slot = ((row&1)*4 + kh*2+lk2) ^ (q&7).
    // (wm*128, mi*32, wn*64, ni*32 are all even and q-multiples of 8 ->
    //  q&7 = (lr5>>1)&7, lane-only; mi stride = 16 q's = 2048 B.)
    const int lr5 = lane & 31;
    const int lk2 = lane >> 5;   // 0..1
    const int lrh = lr5 >> 1;    // 0..15
    const int lp  = lr5 & 1;
    int a_addr[2], b_addr[2];
#pragma unroll
    for (int kh = 0; kh < 2; ++kh) {
        const int slot = (((lp * 4) + (kh * 2 + lk2)) ^ (lrh & 7)) * 16;
        a_addr[kh] = wm * 8192 + lrh * 128 + slot;
        b_addr[kh] = ABUF + wn * 4096 + lrh * 128 + slot;
    }
    const char* sb = (const char*)u.raw;

    // ---- stage one BK=32 tile t into buffer (t&1): 24 chunks, 6 per wave ----
    auto stage = [&](int t) {
        const int bb = (t & 1) * BUFB;
        const int k0 = t * BK;
#pragma unroll
        for (int c = 0; c < 4; ++c) {          // A: 16 chunks of 16 rows
            const int ch = wave + c * 4;
            const __bf16* g = Ag + (size_t)(bm0 + ch * 16 + arow) * KDIM + k0 + acol;
            __builtin_amdgcn_global_load_lds(
                (__attribute__((address_space(1))) void*)g,
                (__attribute__((address_space(3))) void*)&u.raw[bb + ch * 1024],
                16, 0, 0);
        }
#pragma unroll
        for (int c = 0; c < 2; ++c) {          // B: 8 chunks of 16 rows
            const int ch = wave + c * 4;
            const __bf16* g = Bg + (size_t)(bn0 + ch * 16 + arow) * KDIM + k0 + acol;
            __builtin_amdgcn_global_load_lds(
                (__attribute__((address_space(1))) void*)g,
                (__attribute__((address_space(3))) void*)&u.raw[bb + ABUF + ch * 1024],
                16, 0, 0);
        }
    };

    // ---- prologue: tile 0 staged and drained (once) ----
    stage(0);
    __syncthreads();   // implicit vmcnt(0): all waves' tile-0 DMAs landed

    // ---- main loop: stage(t+1) FIRST, compute(t), barrier ----
    // Safety (plain __syncthreads semantics, no inline asm):
    //  - stage(t+1) writes nbuf; last reads of nbuf were compute(t-1),
    //    lgkm-drained at the barrier ending iter t-1.  (WAR ok)
    //  - compute(t) reads cbuf; every wave's stage(t) DMA was drained by the
    //    implicit vmcnt(0) of the barrier ending iter t-1.  (RAW ok)
    //  - this iter's barrier drains stage(t+1) AFTER compute(t) -> latency
    //    hidden under 12 ds_read_b128 + 16 MFMA.
    for (int t = 0; t < NT; ++t) {
        if (t + 1 < NT) stage(t + 1);

        const int cb = (t & 1) * BUFB;
#pragma unroll
        for (int kh = 0; kh < 2; ++kh) {
            bf16x8 af[4], bfr[2];
#pragma unroll
            for (int mi = 0; mi < 4; ++mi)
                af[mi] = *(const bf16x8*)(sb + cb + a_addr[kh] + mi * 2048);
#pragma unroll
            for (int ni = 0; ni < 2; ++ni)
                bfr[ni] = *(const bf16x8*)(sb + cb + b_addr[kh] + ni * 2048);
#pragma unroll
            for (int mi = 0; mi < 4; ++mi)
#pragma unroll
                for (int ni = 0; ni < 2; ++ni)
                    acc[mi][ni] = __builtin_amdgcn_mfma_f32_32x32x16_bf16(
                        af[mi], bfr[ni], acc[mi][ni], 0, 0, 0);
        }
        __syncthreads();
    }

    // ---- epilogue: per-neuron MLP over A=4 adjacent z columns (as R3) ----
    const int t = bn0 >> 10;  // cell type, block-uniform
    float w1[32], b1[8], w2[8];
#pragma unroll
    for (int i = 0; i < 32; ++i) w1[i] = cw1[t * 32 + i];
#pragma unroll
    for (int i = 0; i < 8; ++i) { b1[i] = cb1[t * 8 + i]; w2[i] = cw2[t * 8 + i]; }
    const float b2 = cb2[t];

    float bcol[2];
#pragma unroll
    for (int ni = 0; ni < 2; ++ni)
        bcol[ni] = bias[bn0 + wn * 64 + ni * 32 + lr5];

    const float L2E2 = 2.885390081777927f;  // 2*log2(e)

#pragma unroll
    for (int h = 0; h < 4; ++h) {  // 64-row slabs
        if (wm == (h >> 1)) {
            const int mi0 = (h & 1) * 2;
#pragma unroll
            for (int dmi = 0; dmi < 2; ++dmi) {
                const int mi = mi0 + dmi;
#pragma unroll
                for (int ni = 0; ni < 2; ++ni) {
                    const int n = wn * 64 + ni * 32 + lr5;
#pragma unroll
                    for (int g = 0; g < 4; ++g) {
                        // C/D 32x32 layout: col=lane&31, row=(reg&3)+8*(reg>>2)+4*(lane>>5)
                        const int rb = dmi * 32 + g * 8 + lk2 * 4;
                        u.z[(rb + 0) * ZSTRIDE + n] = acc[mi][ni][g * 4 + 0] + bcol[ni];
                        u.z[(rb + 1) * ZSTRIDE + n] = acc[mi][ni][g * 4 + 1] + bcol[ni];
                        u.z[(rb + 2) * ZSTRIDE + n] = acc[mi][ni][g * 4 + 2] + bcol[ni];
                        u.z[(rb + 3) * ZSTRIDE + n] = acc[mi][ni][g * 4 + 3] + bcol[ni];
                    }
                }
            }
        }
        __syncthreads();

        // 64 rows x 32 neurons = 2048 outputs; 8 per thread
#pragma unroll
        for (int it = 0; it < 8; ++it) {
            const int i = tid + it * 256;
            const int q = i & 31;       // neuron within block
            const int r = i >> 5;       // row within slab
            f32x4 z = *(const f32x4*)&u.z[r * ZSTRIDE + 4 * q];
            float o = 0.f;
#pragma unroll
            for (int hh = 0; hh < 8; ++hh) {
                float pre = z[0] * w1[0 * 8 + hh] + z[1] * w1[1 * 8 + hh]
                          + z[2] * w1[2 * 8 + hh] + z[3] * w1[3 * 8 + hh] + b1[hh];
                float e = __builtin_amdgcn_exp2f(pre * L2E2);        // e^(2*pre)
                float th = 1.0f - 2.0f * __builtin_amdgcn_rcpf(e + 1.0f);
                o += th * w2[hh];
            }
            o += b2;
            out[(size_t)(bm0 + h * 64 + r) * 1024 + (bn0 >> 2) + q] = o;
        }
        __syncthreads();
    }
}

extern "C" void kernel_launch(void* const* d_in, const int* in_sizes, int n_in,
                              void* d_out, int out_size, void* d_ws, size_t ws_size,
                              hipStream_t stream) {
    const float* x    = (const float*)d_in[0];
    const float* w    = (const float*)d_in[1];
    const float* bias = (const float*)d_in[2];
    const float* cw1  = (const float*)d_in[3];
    const float* cb1  = (const float*)d_in[4];
    const float* cw2  = (const float*)d_in[5];
    const float* cb2  = (const float*)d_in[6];
    float* out = (float*)d_out;

    __bf16* xb = (__bf16*)d_ws;                       // 8192*1024 bf16 = 16 MB
    __bf16* wb = xb + (size_t)8192 * 1024;            // 4096*1024 bf16 = 8 MB

    cvt_bf16_kernel<<<(XN8 + WN8) / 256, 256, 0, stream>>>(x, w, xb, wb);

    dim3 grid(4096 / BN, 8192 / BM);  // (32, 32)
    fused_gemm_mlp_kernel<<<grid, 256, 0, stream>>>(xb, wb, bias, cw1, cb1, cw2, cb2, out);
}

// Round 7
// 190.788 us; speedup vs baseline: 1.0527x; 1.0066x over previous
//
#include <hip/hip_runtime.h>

// DenseLayerWithComplexNeurons: out = per-cell-type-MLP( x @ W^T + b )
// M = B*S = 8192, K = DIN = 1024, N = A*DOUT = 4096, DOUT = 1024
// T = 4 cell types, G = 256 neurons/type, A = 4, H = 8.
//
// Round 3: 256x128 BK=64 2-barrier loop. 101.6 us (MfmaUtil 29%).
// Rounds 4-7: 256x256 1-block/CU pipelines: 134/118/FAIL/113 us. Lockstep
//   of 8 waves behind one barrier chain loses to 2-block TLP.
// Round 8: launch_bounds(256,3): acc spills (VGPR 104->84, +23MB scratch).
//   113.5 us. 2 blocks/CU is register-structural (128 acc floats/thread).
// Round 9: BK=32 double-buffer, stage(t+1)->compute(t)->barrier: DMA drain
//   hidden under compute. 97.4 us, MfmaUtil 30.4%, no spills.
// Round 10: lane-local epilogue via weight-row permutation. cvt writes wb
//   with row perm f(4q+a) = 128*(q>>5) + 32a + (q&31), so col(lane&31) of
//   the 4 B-subtiles a=0..3 holds the 4 arity components of neuron q.
//   Wave tile reshaped 128x64 -> 64x128 (2mi x 4a; same reads/MFMA ratio,
//   same 128 acc VGPRs). MLP is now fully in-register: zero epilogue LDS,
//   zero epilogue barriers, no z-write divergence; bias = one f32x4/lane;
//   out stores wave-coalesced (lanes 0-31 = consecutive neurons).

typedef __bf16 bf16x8 __attribute__((ext_vector_type(8)));
typedef float f32x4 __attribute__((ext_vector_type(4)));
typedef float f32x16 __attribute__((ext_vector_type(16)));

#define BM 256
#define BN 128
#define BK 32
#define KDIM 1024
#define NT 32                        // K / BK
#define ABUF 16384                   // A bytes per buffer (256 rows x 32 k x 2B)
#define BUFB 24576                   // per-buffer bytes: A 16K + B 8K
#define XN8 (8192 * 1024 / 8)
#define WN8 (4096 * 1024 / 8)

__global__ __launch_bounds__(256) void cvt_bf16_kernel(
    const float* __restrict__ x, const float* __restrict__ w,
    __bf16* __restrict__ xb, __bf16* __restrict__ wb) {
    int i = blockIdx.x * 256 + threadIdx.x;
    const float* src;
    __bf16* dst;
    int j, jdst;
    if (i < XN8) { src = x; dst = xb; j = i; jdst = i; }
    else {
        src = w; dst = wb; j = i - XN8;
        // W row permutation: row r = 4q+a  ->  128*(q>>5) + 32*a + (q&31)
        const int r  = j >> 7;          // 1024 cols = 128 chunks of 8
        const int c8 = j & 127;
        const int q  = r >> 2;
        const int a  = r & 3;
        const int rn = ((q >> 5) << 7) + (a << 5) + (q & 31);
        jdst = (rn << 7) + c8;
    }
    const f32x4* p = (const f32x4*)src + 2 * (size_t)j;
    f32x4 a = p[0], b = p[1];
    bf16x8 o;
    o[0] = (__bf16)a[0]; o[1] = (__bf16)a[1]; o[2] = (__bf16)a[2]; o[3] = (__bf16)a[3];
    o[4] = (__bf16)b[0]; o[5] = (__bf16)b[1]; o[6] = (__bf16)b[2]; o[7] = (__bf16)b[3];
    ((bf16x8*)dst)[jdst] = o;
}

__global__ __launch_bounds__(256, 2) void fused_gemm_mlp_kernel(
    const __bf16* __restrict__ Ag,   // [8192][1024] bf16 (x)
    const __bf16* __restrict__ Bg,   // [4096][1024] bf16 (perm'd weight, B^T layout)
    const float* __restrict__ bias,  // [4096] (original order)
    const float* __restrict__ cw1,   // [4][4][8]
    const float* __restrict__ cb1,   // [4][8]
    const float* __restrict__ cw2,   // [4][8]
    const float* __restrict__ cb2,   // [4]
    float* __restrict__ out)         // [8192][1024]
{
    __shared__ __align__(16) unsigned char raw[2 * BUFB];   // 49152 B

    const int tid  = threadIdx.x;
    const int wave = tid >> 6;       // 0..3 = m quarter (64 rows each)
    const int lane = tid & 63;
    const int wm = wave;
    const int bn0 = blockIdx.x * BN; // n offset in [0,4096)
    const int bm0 = blockIdx.y * BM; // m offset in [0,8192)

    f32x16 acc[2][4] = {};           // 2 m-tiles x 4 a-subtiles of 32x32

    // ---- staging lane mapping (row-pair physical rows; verified R9) ----
    // 1KB DMA chunk = 16 rows (8 row-pairs x 128B). Lane i writes byte 16*i:
    // q_loc=i>>3, slot=i&7; source: s_log=slot^q_loc, row=2q_loc+(s_log>>2),
    // col16=s_log&3. Global (R,c) lands at chunk*1024 + ((R>>1)&7)*128 +
    // (((R&1)*4+c)^((R>>1)&7))*16 == fragment address below.
    const int qloc = lane >> 3;
    const int slog = (lane & 7) ^ qloc;
    const int arow = 2 * qloc + (slog >> 2);
    const int acol = (slog & 3) * 8;

    // ---- fragment LDS byte addresses (buffer-relative) ----
    // MFMA 32x32x16: row = lane&31, k = kh*16 + (lane>>5)*8 + i.
    // A row = wm*64 + mi*32 + lr5 -> wm*4096 + mi*2048 + lrh*128 + slot
    // B row = a*32 + lr5          -> ABUF + a*2048 + lrh*128 + slot
    const int lr5 = lane & 31;
    const int lk2 = lane >> 5;   // 0..1
    const int lrh = lr5 >> 1;    // 0..15
    const int lp  = lr5 & 1;
    int a_addr[2], b_addr[2];
#pragma unroll
    for (int kh = 0; kh < 2; ++kh) {
        const int slot = (((lp * 4) + (kh * 2 + lk2)) ^ (lrh & 7)) * 16;
        a_addr[kh] = wm * 4096 + lrh * 128 + slot;
        b_addr[kh] = ABUF + lrh * 128 + slot;
    }
    const char* sb = (const char*)raw;

    // ---- stage one BK=32 tile t into buffer (t&1): 24 chunks, 6 per wave ----
    auto stage = [&](int t) {
        const int bb = (t & 1) * BUFB;
        const int k0 = t * BK;
#pragma unroll
        for (int c = 0; c < 4; ++c) {          // A: 16 chunks of 16 rows
            const int ch = wave + c * 4;
            const __bf16* g = Ag + (size_t)(bm0 + ch * 16 + arow) * KDIM + k0 + acol;
            __builtin_amdgcn_global_load_lds(
                (__attribute__((address_space(1))) void*)g,
                (__attribute__((address_space(3))) void*)&raw[bb + ch * 1024],
                16, 0, 0);
        }
#pragma unroll
        for (int c = 0; c < 2; ++c) {          // B: 8 chunks of 16 rows
            const int ch = wave + c * 4;
            const __bf16* g = Bg + (size_t)(bn0 + ch * 16 + arow) * KDIM + k0 + acol;
            __builtin_amdgcn_global_load_lds(
                (__attribute__((address_space(1))) void*)g,
                (__attribute__((address_space(3))) void*)&raw[bb + ABUF + ch * 1024],
                16, 0, 0);
        }
    };

    // ---- prologue: tile 0 staged and drained ----
    stage(0);
    __syncthreads();

    // ---- main loop: stage(t+1) -> compute(t) -> barrier (verified R9) ----
    for (int t = 0; t < NT; ++t) {
        if (t + 1 < NT) stage(t + 1);

        const int cb = (t & 1) * BUFB;
#pragma unroll
        for (int kh = 0; kh < 2; ++kh) {
            bf16x8 af[2], bfr[4];
#pragma unroll
            for (int mi = 0; mi < 2; ++mi)
                af[mi] = *(const bf16x8*)(sb + cb + a_addr[kh] + mi * 2048);
#pragma unroll
            for (int a = 0; a < 4; ++a)
                bfr[a] = *(const bf16x8*)(sb + cb + b_addr[kh] + a * 2048);
#pragma unroll
            for (int mi = 0; mi < 2; ++mi)
#pragma unroll
                for (int a = 0; a < 4; ++a)
                    acc[mi][a] = __builtin_amdgcn_mfma_f32_32x32x16_bf16(
                        af[mi], bfr[a], acc[mi][a], 0, 0, 0);
        }
        __syncthreads();
    }

    // ---- epilogue: fully lane-local per-neuron MLP (no LDS, no barriers) ----
    // Lane (lr5) owns neuron q = bn0/4 + lr5; acc[mi][a][g] = z(row, 4q+a)
    // with row = wm*64 + mi*32 + (g&3) + 8*(g>>2) + 4*lk2.
    const int tct = bn0 >> 10;  // cell type, block-uniform
    float w1[32], b1[8], w2[8];
#pragma unroll
    for (int i = 0; i < 32; ++i) w1[i] = cw1[tct * 32 + i];
#pragma unroll
    for (int i = 0; i < 8; ++i) { b1[i] = cb1[tct * 8 + i]; w2[i] = cw2[tct * 8 + i]; }
    const float b2 = cb2[tct];

    const f32x4 bz = *(const f32x4*)&bias[bn0 + 4 * lr5];   // components a=0..3

    const float L2E2 = 2.885390081777927f;  // 2*log2(e)
    float* outp = out + (size_t)(bm0 + wm * 64 + 4 * lk2) * 1024 + (bn0 >> 2) + lr5;

#pragma unroll
    for (int mi = 0; mi < 2; ++mi) {
#pragma unroll
        for (int g = 0; g < 16; ++g) {
            const float z0 = acc[mi][0][g] + bz[0];
            const float z1 = acc[mi][1][g] + bz[1];
            const float z2 = acc[mi][2][g] + bz[2];
            const float z3 = acc[mi][3][g] + bz[3];
            float o = 0.f;
#pragma unroll
            for (int hh = 0; hh < 8; ++hh) {
                float pre = z0 * w1[0 * 8 + hh] + z1 * w1[1 * 8 + hh]
                          + z2 * w1[2 * 8 + hh] + z3 * w1[3 * 8 + hh] + b1[hh];
                float e = __builtin_amdgcn_exp2f(pre * L2E2);        // e^(2*pre)
                float th = 1.0f - 2.0f * __builtin_amdgcn_rcpf(e + 1.0f);
                o += th * w2[hh];
            }
            o += b2;
            const int row = mi * 32 + (g & 3) + 8 * (g >> 2);  // + wm*64 + 4*lk2 in outp
            outp[(size_t)row * 1024] = o;
        }
    }
}

extern "C" void kernel_launch(void* const* d_in, const int* in_sizes, int n_in,
                              void* d_out, int out_size, void* d_ws, size_t ws_size,
                              hipStream_t stream) {
    const float* x    = (const float*)d_in[0];
    const float* w    = (const float*)d_in[1];
    const float* bias = (const float*)d_in[2];
    const float* cw1  = (const float*)d_in[3];
    const float* cb1  = (const float*)d_in[4];
    const float* cw2  = (const float*)d_in[5];
    const float* cb2  = (const float*)d_in[6];
    float* out = (float*)d_out;

    __bf16* xb = (__bf16*)d_ws;                       // 8192*1024 bf16 = 16 MB
    __bf16* wb = xb + (size_t)8192 * 1024;            // 4096*1024 bf16 = 8 MB

    cvt_bf16_kernel<<<(XN8 + WN8) / 256, 256, 0, stream>>>(x, w, xb, wb);

    dim3 grid(4096 / BN, 8192 / BM);  // (32, 32)
    fused_gemm_mlp_kernel<<<grid, 256, 0, stream>>>(xb, wb, bias, cw1, cb1, cw2, cb2, out);
}

// Round 8
// 185.333 us; speedup vs baseline: 1.0837x; 1.0294x over previous
//
#include <hip/hip_runtime.h>

// DenseLayerWithComplexNeurons: out = per-cell-type-MLP( x @ W^T + b )
// M = B*S = 8192, K = DIN = 1024, N = A*DOUT = 4096, DOUT = 1024
// T = 4 cell types, G = 256 neurons/type, A = 4, H = 8.
//
// Round 3: 256x128 BK=64 2-barrier loop. 101.6 us (MfmaUtil 29%).
// Rounds 4-7: 256x256 1-block/CU pipelines: 134/118/FAIL/113 us. Lockstep
//   of 8 waves behind one barrier chain loses to 2-block TLP.
// Round 8: launch_bounds(256,3): acc spills. 113.5 us. 2 blocks/CU is
//   register-structural (128 acc floats/thread).
// Round 9: BK=32 double-buffer, stage(t+1)->compute(t)->syncthreads. 97.4 us.
// Round 10: lane-local epilogue via W-row permutation (zero-LDS epilogue).
//   96.6 us -- epilogue was ~1 us, already hidden. Main loop IS the 96 us.
//   Pipe budget/CU: MFMA 65K cyc, LDS read+DMA ~98K cyc, wall 232K cyc.
//   Residual: __syncthreads' implicit vmcnt(0) drains the JUST-ISSUED
//   stage DMAs every iter -> ~400 cyc exposed latency x 128 iters/CU.
// Round 11: T4. Triple buffer (3x24KB=72KB, still 2 blocks/CU), stage(t+2),
//   end iter with counted vmcnt(6) + raw s_barrier: only tile t+1 drained,
//   tile t+2's 6 loads stay in flight across the barrier (~2 compute
//   phases of latency budget). Tail: vmcnt(0) at t=NT-2; no barrier after
//   last compute (epilogue is register-only). Everything else = R10.

typedef __bf16 bf16x8 __attribute__((ext_vector_type(8)));
typedef float f32x4 __attribute__((ext_vector_type(4)));
typedef float f32x16 __attribute__((ext_vector_type(16)));

#define BM 256
#define BN 128
#define BK 32
#define KDIM 1024
#define NT 32                        // K / BK
#define ABUF 16384                   // A bytes per buffer (256 rows x 32 k x 2B)
#define BUFB 24576                   // per-buffer bytes: A 16K + B 8K
#define NBUF 3
#define XN8 (8192 * 1024 / 8)
#define WN8 (4096 * 1024 / 8)

__global__ __launch_bounds__(256) void cvt_bf16_kernel(
    const float* __restrict__ x, const float* __restrict__ w,
    __bf16* __restrict__ xb, __bf16* __restrict__ wb) {
    int i = blockIdx.x * 256 + threadIdx.x;
    const float* src;
    __bf16* dst;
    int j, jdst;
    if (i < XN8) { src = x; dst = xb; j = i; jdst = i; }
    else {
        src = w; dst = wb; j = i - XN8;
        // W row permutation: row r = 4q+a  ->  128*(q>>5) + 32*a + (q&31)
        const int r  = j >> 7;          // 1024 cols = 128 chunks of 8
        const int c8 = j & 127;
        const int q  = r >> 2;
        const int a  = r & 3;
        const int rn = ((q >> 5) << 7) + (a << 5) + (q & 31);
        jdst = (rn << 7) + c8;
    }
    const f32x4* p = (const f32x4*)src + 2 * (size_t)j;
    f32x4 a = p[0], b = p[1];
    bf16x8 o;
    o[0] = (__bf16)a[0]; o[1] = (__bf16)a[1]; o[2] = (__bf16)a[2]; o[3] = (__bf16)a[3];
    o[4] = (__bf16)b[0]; o[5] = (__bf16)b[1]; o[6] = (__bf16)b[2]; o[7] = (__bf16)b[3];
    ((bf16x8*)dst)[jdst] = o;
}

#define FENCE() asm volatile("" ::: "memory")
#define BARRIER() do { FENCE(); __builtin_amdgcn_s_barrier(); FENCE(); } while (0)
#define VMCNT(n) asm volatile("s_waitcnt vmcnt(" #n ")" ::: "memory")

__global__ __launch_bounds__(256, 2) void fused_gemm_mlp_kernel(
    const __bf16* __restrict__ Ag,   // [8192][1024] bf16 (x)
    const __bf16* __restrict__ Bg,   // [4096][1024] bf16 (perm'd weight, B^T layout)
    const float* __restrict__ bias,  // [4096] (original order)
    const float* __restrict__ cw1,   // [4][4][8]
    const float* __restrict__ cb1,   // [4][8]
    const float* __restrict__ cw2,   // [4][8]
    const float* __restrict__ cb2,   // [4]
    float* __restrict__ out)         // [8192][1024]
{
    __shared__ __align__(16) unsigned char raw[NBUF * BUFB];   // 73728 B

    const int tid  = threadIdx.x;
    const int wave = tid >> 6;       // 0..3 = m quarter (64 rows each)
    const int lane = tid & 63;
    const int wm = wave;
    const int bn0 = blockIdx.x * BN; // n offset in [0,4096)
    const int bm0 = blockIdx.y * BM; // m offset in [0,8192)

    f32x16 acc[2][4] = {};           // 2 m-tiles x 4 a-subtiles of 32x32

    // ---- staging lane mapping (row-pair physical rows; verified R9/R10) ----
    // 1KB DMA chunk = 16 rows (8 row-pairs x 128B). Lane i writes byte 16*i:
    // q_loc=i>>3, slot=i&7; source: s_log=slot^q_loc, row=2q_loc+(s_log>>2),
    // col16=s_log&3. Global (R,c) lands at chunk*1024 + ((R>>1)&7)*128 +
    // (((R&1)*4+c)^((R>>1)&7))*16 == fragment address below.
    const int qloc = lane >> 3;
    const int slog = (lane & 7) ^ qloc;
    const int arow = 2 * qloc + (slog >> 2);
    const int acol = (slog & 3) * 8;

    // ---- fragment LDS byte addresses (buffer-relative; verified R10) ----
    // MFMA 32x32x16: row = lane&31, k = kh*16 + (lane>>5)*8 + i.
    // A row = wm*64 + mi*32 + lr5 -> wm*4096 + mi*2048 + lrh*128 + slot
    // B row = a*32 + lr5          -> ABUF + a*2048 + lrh*128 + slot
    const int lr5 = lane & 31;
    const int lk2 = lane >> 5;   // 0..1
    const int lrh = lr5 >> 1;    // 0..15
    const int lp  = lr5 & 1;
    int a_addr[2], b_addr[2];
#pragma unroll
    for (int kh = 0; kh < 2; ++kh) {
        const int slot = (((lp * 4) + (kh * 2 + lk2)) ^ (lrh & 7)) * 16;
        a_addr[kh] = wm * 4096 + lrh * 128 + slot;
        b_addr[kh] = ABUF + lrh * 128 + slot;
    }
    const char* sb = (const char*)raw;

    // ---- stage one BK=32 tile t into buffer base bb: 24 chunks, 6/wave ----
    auto stage = [&](int t, int bb) {
        const int k0 = t * BK;
#pragma unroll
        for (int c = 0; c < 4; ++c) {          // A: 16 chunks of 16 rows
            const int ch = wave + c * 4;
            const __bf16* g = Ag + (size_t)(bm0 + ch * 16 + arow) * KDIM + k0 + acol;
            __builtin_amdgcn_global_load_lds(
                (__attribute__((address_space(1))) void*)g,
                (__attribute__((address_space(3))) void*)&raw[bb + ch * 1024],
                16, 0, 0);
        }
#pragma unroll
        for (int c = 0; c < 2; ++c) {          // B: 8 chunks of 16 rows
            const int ch = wave + c * 4;
            const __bf16* g = Bg + (size_t)(bn0 + ch * 16 + arow) * KDIM + k0 + acol;
            __builtin_amdgcn_global_load_lds(
                (__attribute__((address_space(1))) void*)g,
                (__attribute__((address_space(3))) void*)&raw[bb + ABUF + ch * 1024],
                16, 0, 0);
        }
    };

    // ---- prologue: tiles 0,1 staged; drain tile 0 only (counted) ----
    stage(0, 0);
    stage(1, BUFB);
    VMCNT(6);          // 12 outstanding -> drain tile 0's 6, keep tile 1 in flight
    BARRIER();

    // ---- main loop ----
    // Per-wave outstanding at end of iter t: tile t+1 (6, issued t-1) +
    // tile t+2 (6, issued this iter) = 12. vmcnt(6) drains exactly tile t+1
    // for every wave; barrier publishes. Stage(t+2) overwrites the buffer
    // of tile t-1, whose ds_reads were consumed before the iter t-1 barrier.
    int cb = 0;             // buffer of tile t
    int pb = 2 * BUFB;      // buffer for tile t+2
    for (int t = 0; t < NT; ++t) {
        if (t + 2 < NT) stage(t + 2, pb);

#pragma unroll
        for (int kh = 0; kh < 2; ++kh) {
            bf16x8 af[2], bfr[4];
#pragma unroll
            for (int mi = 0; mi < 2; ++mi)
                af[mi] = *(const bf16x8*)(sb + cb + a_addr[kh] + mi * 2048);
#pragma unroll
            for (int a = 0; a < 4; ++a)
                bfr[a] = *(const bf16x8*)(sb + cb + b_addr[kh] + a * 2048);
#pragma unroll
            for (int mi = 0; mi < 2; ++mi)
#pragma unroll
                for (int a = 0; a < 4; ++a)
                    acc[mi][a] = __builtin_amdgcn_mfma_f32_32x32x16_bf16(
                        af[mi], bfr[a], acc[mi][a], 0, 0, 0);
        }

        if (t + 2 < NT)      { VMCNT(6); BARRIER(); }   // steady state
        else if (t + 1 < NT) { VMCNT(0); BARRIER(); }   // t=NT-2: drain last tile
        // t=NT-1: no waits, no barrier (epilogue is register-only)

        cb += BUFB; if (cb == NBUF * BUFB) cb = 0;
        pb += BUFB; if (pb == NBUF * BUFB) pb = 0;
    }

    // ---- epilogue: fully lane-local per-neuron MLP (verified R10) ----
    // Lane (lr5) owns neuron q = bn0/4 + lr5; acc[mi][a][g] = z(row, 4q+a)
    // with row = wm*64 + mi*32 + (g&3) + 8*(g>>2) + 4*lk2.
    const int tct = bn0 >> 10;  // cell type, block-uniform
    float w1[32], b1[8], w2[8];
#pragma unroll
    for (int i = 0; i < 32; ++i) w1[i] = cw1[tct * 32 + i];
#pragma unroll
    for (int i = 0; i < 8; ++i) { b1[i] = cb1[tct * 8 + i]; w2[i] = cw2[tct * 8 + i]; }
    const float b2 = cb2[tct];

    const f32x4 bz = *(const f32x4*)&bias[bn0 + 4 * lr5];   // components a=0..3

    const float L2E2 = 2.885390081777927f;  // 2*log2(e)
    float* outp = out + (size_t)(bm0 + wm * 64 + 4 * lk2) * 1024 + (bn0 >> 2) + lr5;

#pragma unroll
    for (int mi = 0; mi < 2; ++mi) {
#pragma unroll
        for (int g = 0; g < 16; ++g) {
            const float z0 = acc[mi][0][g] + bz[0];
            const float z1 = acc[mi][1][g] + bz[1];
            const float z2 = acc[mi][2][g] + bz[2];
            const float z3 = acc[mi][3][g] + bz[3];
            float o = 0.f;
#pragma unroll
            for (int hh = 0; hh < 8; ++hh) {
                float pre = z0 * w1[0 * 8 + hh] + z1 * w1[1 * 8 + hh]
                          + z2 * w1[2 * 8 + hh] + z3 * w1[3 * 8 + hh] + b1[hh];
                float e = __builtin_amdgcn_exp2f(pre * L2E2);        // e^(2*pre)
                float th = 1.0f - 2.0f * __builtin_amdgcn_rcpf(e + 1.0f);
                o += th * w2[hh];
            }
            o += b2;
            const int row = mi * 32 + (g & 3) + 8 * (g >> 2);  // + wm*64 + 4*lk2 in outp
            outp[(size_t)row * 1024] = o;
        }
    }
}

extern "C" void kernel_launch(void* const* d_in, const int* in_sizes, int n_in,
                              void* d_out, int out_size, void* d_ws, size_t ws_size,
                              hipStream_t stream) {
    const float* x    = (const float*)d_in[0];
    const float* w    = (const float*)d_in[1];
    const float* bias = (const float*)d_in[2];
    const float* cw1  = (const float*)d_in[3];
    const float* cb1  = (const float*)d_in[4];
    const float* cw2  = (const float*)d_in[5];
    const float* cb2  = (const float*)d_in[6];
    float* out = (float*)d_out;

    __bf16* xb = (__bf16*)d_ws;                       // 8192*1024 bf16 = 16 MB
    __bf16* wb = xb + (size_t)8192 * 1024;            // 4096*1024 bf16 = 8 MB

    cvt_bf16_kernel<<<(XN8 + WN8) / 256, 256, 0, stream>>>(x, w, xb, wb);

    dim3 grid(4096 / BN, 8192 / BM);  // (32, 32)
    fused_gemm_mlp_kernel<<<grid, 256, 0, stream>>>(xb, wb, bias, cw1, cb1, cw2, cb2, out);
}